// Round 10
// baseline (180.352 us; speedup 1.0000x reference)
//
#include <hip/hip_runtime.h>

typedef unsigned short u16;
typedef __attribute__((ext_vector_type(8))) short short8;
typedef __attribute__((ext_vector_type(4))) short short4v;
typedef __attribute__((ext_vector_type(2))) int int2v;
typedef __attribute__((ext_vector_type(4))) float f32x4;

#define DIM   768
#define HEADS 12
#define HD    64
#define BATCH 8
#define SEQ   1024
#define MTOK  (BATCH*SEQ)   /* 8192 */
#define NQKV  (3*DIM)       /* 2304 */
#define KP    72            /* attn LDS row stride: 144B = 9*16B -> b128-aligned, even 8-lane/span */
#define EPAD  66            /* gemm epilogue stage stride */
#define PSZ   ((size_t)BATCH*HEADS*SEQ*HD)   /* one of q/k/v */
#define SCQ   0.1803368801f /* hd^-0.5 * log2(e), folded into stored q */

__device__ __forceinline__ u16 f2bf(float f) {
  unsigned x = __float_as_uint(f);
  x += 0x7fffu + ((x >> 16) & 1u);      // RNE
  return (u16)(x >> 16);
}

__device__ __forceinline__ void gload16(const u16* g, u16* l) {
  __builtin_amdgcn_global_load_lds(
      (const __attribute__((address_space(1))) unsigned int*)g,
      (__attribute__((address_space(3))) unsigned int*)l, 16, 0, 0);
}

// ---------------- fused conversions: x->bf16, Wqkv^T, Wproj^T ----------------
#define XBLK 6144            /* MTOK*DIM/4/256 */
#define QTBLK 1728           /* (NQKV/32)*(DIM/32) */
__global__ void cvt_all_k(const float* __restrict__ x,
                          const float* __restrict__ Wqkv,
                          const float* __restrict__ Wproj,
                          u16* __restrict__ xb, u16* __restrict__ wqkvt,
                          u16* __restrict__ wprojt) {
  __shared__ u16 tile[32][33];
  const int blk = blockIdx.x;
  if (blk < XBLK) {
    const int i = blk * 256 + threadIdx.x;
    float4 f = ((const float4*)x)[i];
    short4v o;
    o.x = (short)f2bf(f.x); o.y = (short)f2bf(f.y);
    o.z = (short)f2bf(f.z); o.w = (short)f2bf(f.w);
    ((short4v*)xb)[i] = o;
    return;
  }
  const float* in; u16* out; int K, N, n0, k0;
  if (blk < XBLK + QTBLK) {
    const int t = blk - XBLK;
    in = Wqkv; out = wqkvt; K = DIM; N = NQKV;
    n0 = (t % (NQKV / 32)) * 32; k0 = (t / (NQKV / 32)) * 32;
  } else {
    const int t = blk - XBLK - QTBLK;
    in = Wproj; out = wprojt; K = DIM; N = DIM;
    n0 = (t % (DIM / 32)) * 32; k0 = (t / (DIM / 32)) * 32;
  }
  const int tx = threadIdx.x & 31, ty = threadIdx.x >> 5;
  #pragma unroll
  for (int i = 0; i < 32; i += 8)
    tile[ty + i][tx] = f2bf(in[(size_t)(k0 + ty + i) * N + n0 + tx]);
  __syncthreads();
  #pragma unroll
  for (int i = 0; i < 32; i += 8)
    out[(size_t)(n0 + ty + i) * K + k0 + tx] = tile[tx][ty + i];
}

// ---------------- GEMM1: qkv = x * Wqkv^T + b, 128x128 tile, BK=64 ----------------
// T4 counted-vmcnt on the round-8 BK=64 frame: 2 LDS buffers (64KB), per iter
// STAGE(buf^1, k+1) [8 loads] -> vmcnt(8) (waits ONLY the previous batch; the
// 8 just-issued loads stay in flight across the barrier with a full compute
// phase to land) -> bar -> ds_read -> lgkmcnt(0) -> bar (WAR fence: buf's next
// overwrite is issued only after every wave passed this barrier) -> 32 MFMA.
// This keeps round-8's 32-MFMA-per-barrier amortization (round-9's BK=32 lost
// it) while removing the vmcnt(0) drain round-8 paid at every __syncthreads.
__global__ __launch_bounds__(256)
void gemm_qkv(const u16* __restrict__ A, const u16* __restrict__ Bt,
              const float* __restrict__ bias, u16* __restrict__ qkv) {
  __shared__ __align__(16) u16 smem[8 * 128 * 32];   // 64 KB: 2 half-buffers
  const int w = threadIdx.x >> 6, lane = threadIdx.x & 63;
  const int l15 = lane & 15, quad = lane >> 4;
  const int b_ = blockIdx.x;
  const int xcd = b_ & 7, j = b_ >> 3;
  const int m0 = ((j & 7) * 8 + xcd) * 128;   // 0..63 * 128
  const int n0 = (j >> 3) * 128;              // 0..17 * 128
  const int wm = (w >> 1) * 64, wn = (w & 1) * 64;

  f32x4 acc[4][4] = {};

  const int ar = threadIdx.x >> 2, ak = (threadIdx.x & 3) * 8;
  const u16* ga = A  + (size_t)(m0 + ar) * DIM + ak;
  const u16* gb = Bt + (size_t)(n0 + ar) * DIM + ak;
  const int lo = threadIdx.x * 8;

  auto qstage = [&](int c, int k0) {
    u16* base = smem + c * 16384;
    #pragma unroll
    for (int t = 0; t < 2; ++t) {
      gload16(ga + (size_t)t * 64 * DIM + k0,      base + lo + t * 2048);
      gload16(ga + (size_t)t * 64 * DIM + k0 + 32, base + 4096  + lo + t * 2048);
      gload16(gb + (size_t)t * 64 * DIM + k0,      base + 8192  + lo + t * 2048);
      gload16(gb + (size_t)t * 64 * DIM + k0 + 32, base + 12288 + lo + t * 2048);
    }
  };

  qstage(0, 0);   // batch 0 -> buf0

  #pragma unroll
  for (int it = 0; it < 12; ++it) {
    const int cur = it & 1;
    if (it < 11) qstage(cur ^ 1, (it + 1) * 64);   // batch it+1 -> buf^1
    // wait ONLY batch it (8 loads); batch it+1 stays in flight across the barrier
    if (it < 11) asm volatile("s_waitcnt vmcnt(8)" ::: "memory");
    else         asm volatile("s_waitcnt vmcnt(0)" ::: "memory");
    __builtin_amdgcn_s_barrier();

    const u16* hb = smem + cur * 16384;
    short8 af[4][2], bfr[4][2];
    #pragma unroll
    for (int kh = 0; kh < 2; ++kh) {
      const u16* lAh = hb + kh * 4096;
      const u16* lBh = hb + 8192 + kh * 4096;
      #pragma unroll
      for (int mt = 0; mt < 4; ++mt)
        af[mt][kh] = *(const short8*)&lAh[(wm + mt * 16 + l15) * 32 + quad * 8];
      #pragma unroll
      for (int nt = 0; nt < 4; ++nt)
        bfr[nt][kh] = *(const short8*)&lBh[(wn + nt * 16 + l15) * 32 + quad * 8];
    }

    // WAR fence: all lanes' ds_reads of buf[cur] complete before anyone can
    // issue the DMA that overwrites it (at iter it+1's STAGE)
    asm volatile("s_waitcnt lgkmcnt(0)" ::: "memory");
    __builtin_amdgcn_s_barrier();

    #pragma unroll
    for (int kh = 0; kh < 2; ++kh)
      #pragma unroll
      for (int mt = 0; mt < 4; ++mt)
        #pragma unroll
        for (int nt = 0; nt < 4; ++nt)
          acc[mt][nt] = __builtin_amdgcn_mfma_f32_16x16x32_bf16(af[mt][kh], bfr[nt][kh], acc[mt][nt], 0, 0, 0);
  }

  const int bb = m0 >> 10;
  const int tb0 = (m0 & 1023) + wm;
  const int nh = n0 + wn;
  const int part = nh / DIM, idx = nh - part * DIM;
  const int h = idx >> 6;

  float bnl[4];
  #pragma unroll
  for (int nt = 0; nt < 4; ++nt) bnl[nt] = bias[nh + nt * 16 + l15];

  if (part < 2) {
    u16* dstbase = qkv + part * PSZ + ((size_t)(bb * HEADS + h) * SEQ + tb0) * HD;
    const float qsc = (part == 0) ? SCQ : 1.0f;
    const int erow = lane >> 3, ec8 = (lane & 7) * 8;
    #pragma unroll
    for (int mt = 0; mt < 4; ++mt) {
      u16* ep = smem + w * (16 * EPAD) + (mt & 1) * (4 * 16 * EPAD);
      #pragma unroll
      for (int nt = 0; nt < 4; ++nt)
        #pragma unroll
        for (int r = 0; r < 4; ++r)
          ep[(quad * 4 + r) * EPAD + nt * 16 + l15] = f2bf((acc[mt][nt][r] + bnl[nt]) * qsc);
      #pragma unroll
      for (int j2 = 0; j2 < 2; ++j2) {
        const int trow = j2 * 8 + erow;
        short8 vrow = *(const short8*)&ep[trow * EPAD + ec8];
        *(short8*)(dstbase + (size_t)(mt * 16 + trow) * HD + ec8) = vrow;
      }
    }
  } else {
    u16* vrow0 = qkv + 2 * PSZ + (size_t)(bb * HEADS + h) * HD * SEQ;
    #pragma unroll
    for (int nt = 0; nt < 4; ++nt) {
      const int d = nt * 16 + l15;
      u16* trow = vrow0 + (size_t)d * SEQ + tb0 + quad * 4;
      #pragma unroll
      for (int mt = 0; mt < 4; ++mt) {
        short4v pv;
        pv.x = (short)f2bf(acc[mt][nt][0] + bnl[nt]);
        pv.y = (short)f2bf(acc[mt][nt][1] + bnl[nt]);
        pv.z = (short)f2bf(acc[mt][nt][2] + bnl[nt]);
        pv.w = (short)f2bf(acc[mt][nt][3] + bnl[nt]);
        *(short4v*)(trow + mt * 16) = pv;
      }
    }
  }
}

// ---------------- GEMM2: out = y * Wproj^T + b (fp32 out, 128x128, BK=64) ----------------
// Round-8 proven: 64x64/wave, BK=64 2-phase dbuf, grid 384 (=8x48, XCD-swizzled),
// fully co-resident at 2 blocks/CU.
__global__ __launch_bounds__(256)
void gemm_proj(const u16* __restrict__ A, const u16* __restrict__ Bt,
               const float* __restrict__ bias, float* __restrict__ outF) {
  __shared__ __align__(16) u16 smem[8 * 128 * 32];   // 64 KB: 2 half-buffers
  const int w = threadIdx.x >> 6, lane = threadIdx.x & 63;
  const int l15 = lane & 15, quad = lane >> 4;
  const int b_ = blockIdx.x;
  const int xcd = b_ & 7, j = b_ >> 3;        // j 0..47
  const int m0 = ((j & 7) * 8 + xcd) * 128;   // 0..63 * 128
  const int n0 = (j >> 3) * 128;              // 0..5 * 128
  const int wm = (w >> 1) * 64, wn = (w & 1) * 64;

  f32x4 acc[4][4] = {};

  const int ar = threadIdx.x >> 2, ak = (threadIdx.x & 3) * 8;
  const u16* ga = A  + (size_t)(m0 + ar) * DIM + ak;
  const u16* gb = Bt + (size_t)(n0 + ar) * DIM + ak;
  const int lo = threadIdx.x * 8;

  auto pstage = [&](int c, int k0) {
    u16* base = smem + c * 16384;
    #pragma unroll
    for (int t = 0; t < 2; ++t) {
      gload16(ga + (size_t)t * 64 * DIM + k0,      base + lo + t * 2048);
      gload16(ga + (size_t)t * 64 * DIM + k0 + 32, base + 4096  + lo + t * 2048);
      gload16(gb + (size_t)t * 64 * DIM + k0,      base + 8192  + lo + t * 2048);
      gload16(gb + (size_t)t * 64 * DIM + k0 + 32, base + 12288 + lo + t * 2048);
    }
  };

  pstage(0, 0);
  __syncthreads();

  #pragma unroll
  for (int it = 0; it < 12; ++it) {
    const int cur = it & 1;
    if (it < 11) pstage(cur ^ 1, (it + 1) * 64);
    const u16* hb = smem + cur * 16384;
    #pragma unroll
    for (int kh = 0; kh < 2; ++kh) {
      const u16* lAh = hb + kh * 4096;
      const u16* lBh = hb + 8192 + kh * 4096;
      short8 af[4], bfr[4];
      #pragma unroll
      for (int mt = 0; mt < 4; ++mt)
        af[mt] = *(const short8*)&lAh[(wm + mt * 16 + l15) * 32 + quad * 8];
      #pragma unroll
      for (int nt = 0; nt < 4; ++nt)
        bfr[nt] = *(const short8*)&lBh[(wn + nt * 16 + l15) * 32 + quad * 8];
      #pragma unroll
      for (int mt = 0; mt < 4; ++mt)
        #pragma unroll
        for (int nt = 0; nt < 4; ++nt)
          acc[mt][nt] = __builtin_amdgcn_mfma_f32_16x16x32_bf16(af[mt], bfr[nt], acc[mt][nt], 0, 0, 0);
    }
    __syncthreads();
  }

  #pragma unroll
  for (int nt = 0; nt < 4; ++nt) {
    const int n = n0 + wn + nt * 16 + l15;
    const float bn = bias[n];
    #pragma unroll
    for (int mt = 0; mt < 4; ++mt)
      #pragma unroll
      for (int r = 0; r < 4; ++r) {
        const int m = m0 + wm + mt * 16 + quad * 4 + r;
        outF[(size_t)m * DIM + n] = acc[mt][nt][r] + bn;
      }
  }
}

// ---------------- flash attention: 8 waves = 4 row-groups x 2 key-halves ----------------
// KP=72 (144B rows: 16B-aligned, even 8-lane/span banks); __launch_bounds__(512,4)
// (128-reg cap; (512,6)'s 85-reg cap spilled). LDS-issue-bound structure.
__global__ __launch_bounds__(512, 4)
void attn_k(const u16* __restrict__ qb, const u16* __restrict__ kb,
            const u16* __restrict__ vtb, u16* __restrict__ yb) {
  const int bh = blockIdx.x, qt = blockIdx.y;
  const int tid = threadIdx.x;
  const int w = tid >> 6, lane = tid & 63;
  const int l15 = lane & 15, quad = lane >> 4;
  const int rg = w & 3;          // row-group: 32 rows each
  const int kh = w >> 2;         // key-half: keys kh*32..kh*32+31
  const int nt0 = kh * 2;

  __shared__ __align__(16) u16 smem[27648];   // 55296 B
  u16* lK  = smem;                       // [64][72]  keys x d
  u16* lV  = smem + 4608;                // [64][72]  d x keys
  u16* lPq = smem + 9216 + rg * 2304;    // P rows of this rg: [32][72] (kh halves disjoint cols)
  u16* stg = smem + 18432 + rg * 2304;   // kh=0 epilogue staging [32][72] (bytes 36864+)
  float* fo = (float*)smem;              // epilogue combine [128][68] f32 (bytes 0..34816)

  // Q fragments: rows qt*128 + rg*32 + qg*16 + l15
  const u16* qrow = qb + ((size_t)bh * SEQ + qt * 128 + rg * 32 + l15) * HD;
  short8 aq[2][2];
  #pragma unroll
  for (int qg = 0; qg < 2; ++qg) {
    aq[qg][0] = *(const short8*)(qrow + (size_t)qg * 16 * HD + quad * 8);
    aq[qg][1] = *(const short8*)(qrow + (size_t)qg * 16 * HD + 32 + quad * 8);
  }

  f32x4 o[2][4] = {};     // [qg][d-group] partial PV over this wave's 32 keys
  f32x4 sum[2] = {};      // [qg] partial row-sums (MFMA vs ones)

  const u16* kcbase = kb + (size_t)bh * SEQ * HD;
  const u16* vbase  = vtb + (size_t)bh * HD * SEQ;

  // staging: 512 threads cover each 64x64 u16 tile (one short8 each)
  const int srow = tid >> 3, scol = tid & 7;
  const int sofs = srow * KP + scol * 8;
  const u16* kg = kcbase + tid * 8;
  const u16* vg = vbase + (size_t)srow * SEQ + scol * 8;

  short8 pk = *(const short8*)kg;
  short8 pv = *(const short8*)vg;

  short8 ones;
  #pragma unroll
  for (int i = 0; i < 8; ++i) ones[i] = (short)0x3f80;   // bf16 1.0

  for (int kc = 0; kc < 16; ++kc) {
    *(short8*)&lK[sofs] = pk;
    *(short8*)&lV[sofs] = pv;
    __syncthreads();

    const int kn = (kc < 15) ? kc + 1 : 15;
    pk = *(const short8*)(kg + (size_t)kn * 64 * HD);
    pv = *(const short8*)(vg + kn * 64);

    // K fragments for this wave's 32 keys (shared across qg)
    short8 akf[2][2];
    #pragma unroll
    for (int i = 0; i < 2; ++i) {
      const int key = (nt0 + i) * 16 + l15;
      akf[i][0] = *(const short8*)&lK[key * KP + quad * 8];
      akf[i][1] = *(const short8*)&lK[key * KP + 32 + quad * 8];
    }

    // QK^T + softmax numerators for both qg
    #pragma unroll
    for (int qg = 0; qg < 2; ++qg) {
      f32x4 s0 = {}, s1 = {};
      __builtin_amdgcn_s_setprio(1);
      s0 = __builtin_amdgcn_mfma_f32_16x16x32_bf16(akf[0][0], aq[qg][0], s0, 0, 0, 0);
      s0 = __builtin_amdgcn_mfma_f32_16x16x32_bf16(akf[0][1], aq[qg][1], s0, 0, 0, 0);
      s1 = __builtin_amdgcn_mfma_f32_16x16x32_bf16(akf[1][0], aq[qg][0], s1, 0, 0, 0);
      s1 = __builtin_amdgcn_mfma_f32_16x16x32_bf16(akf[1][1], aq[qg][1], s1, 0, 0, 0);
      __builtin_amdgcn_s_setprio(0);
      #pragma unroll
      for (int i = 0; i < 2; ++i) {
        const f32x4 s = i ? s1 : s0;
        float p0 = __builtin_amdgcn_exp2f(s[0]);
        float p1 = __builtin_amdgcn_exp2f(s[1]);
        float p2 = __builtin_amdgcn_exp2f(s[2]);
        float p3 = __builtin_amdgcn_exp2f(s[3]);
        int2v pkk;
        pkk.x = (int)__builtin_amdgcn_perm(__float_as_uint(p1), __float_as_uint(p0), 0x07060302u);
        pkk.y = (int)__builtin_amdgcn_perm(__float_as_uint(p3), __float_as_uint(p2), 0x07060302u);
        *(int2v*)&lPq[(qg * 16 + l15) * KP + (nt0 + i) * 16 + quad * 4] = pkk;
      }
    }

    // V fragments (this key-half), shared across qg
    short8 bv[4];
    #pragma unroll
    for (int ntd = 0; ntd < 4; ++ntd)
      bv[ntd] = *(const short8*)&lV[(ntd * 16 + l15) * KP + kh * 32 + quad * 8];

    #pragma unroll
    for (int qg = 0; qg < 2; ++qg) {
      const short8 ap = *(const short8*)&lPq[(qg * 16 + l15) * KP + kh * 32 + quad * 8];
      __builtin_amdgcn_s_setprio(1);
      #pragma unroll
      for (int ntd = 0; ntd < 4; ++ntd)
        o[qg][ntd] = __builtin_amdgcn_mfma_f32_16x16x32_bf16(ap, bv[ntd], o[qg][ntd], 0, 0, 0);
      sum[qg] = __builtin_amdgcn_mfma_f32_16x16x32_bf16(ap, ones, sum[qg], 0, 0, 0);
      __builtin_amdgcn_s_setprio(0);
    }
    __syncthreads();
  }

  // ---- combine key-halves: kh=1 publishes partials, kh=0 finishes ----
  if (kh == 1) {
    #pragma unroll
    for (int qg = 0; qg < 2; ++qg)
      #pragma unroll
      for (int r = 0; r < 4; ++r) {
        const int row = rg * 32 + qg * 16 + quad * 4 + r;
        #pragma unroll
        for (int ntd = 0; ntd < 4; ++ntd)
          fo[row * 68 + ntd * 16 + l15] = o[qg][ntd][r];
        if (l15 == 0) fo[row * 68 + 64] = sum[qg][r];
      }
  }
  __syncthreads();

  if (kh == 0) {
    const int b = bh / HEADS, h = bh % HEADS;
    #pragma unroll
    for (int qg = 0; qg < 2; ++qg)
      #pragma unroll
      for (int r = 0; r < 4; ++r) {
        const int lrow = qg * 16 + quad * 4 + r;
        const int row = rg * 32 + lrow;
        const float s = sum[qg][r] + fo[row * 68 + 64];
        const float inv = 1.0f / s;
        #pragma unroll
        for (int ntd = 0; ntd < 4; ++ntd) {
          const float v = (o[qg][ntd][r] + fo[row * 68 + ntd * 16 + l15]) * inv;
          stg[lrow * KP + ntd * 16 + l15] = f2bf(v);
        }
      }
    u16* dst = yb + ((size_t)b * SEQ + qt * 128 + rg * 32) * DIM + h * HD;
    const int erow = lane >> 3, ec8 = (lane & 7) * 8;
    #pragma unroll
    for (int j = 0; j < 4; ++j) {
      const int trow = j * 8 + erow;
      short8 vrow = *(const short8*)&stg[trow * KP + ec8];
      *(short8*)(dst + (size_t)trow * DIM + ec8) = vrow;
    }
  }
}

// ---------------- launcher ----------------
extern "C" void kernel_launch(void* const* d_in, const int* in_sizes, int n_in,
                              void* d_out, int out_size, void* d_ws, size_t ws_size,
                              hipStream_t stream) {
  const float* x     = (const float*)d_in[0];
  const float* Wqkv  = (const float*)d_in[1];
  const float* bqkv  = (const float*)d_in[2];
  const float* Wproj = (const float*)d_in[3];
  const float* bproj = (const float*)d_in[4];
  float* out = (float*)d_out;

  u16* xb     = (u16*)d_ws;                       // 8192*768
  u16* wqkvt  = xb + (size_t)MTOK * DIM;
  u16* wprojt = wqkvt + (size_t)NQKV * DIM;
  u16* qkv_b  = wprojt + (size_t)DIM * DIM;       // q,k: [t][d]; v-slot holds vt [d][t]
  u16* y_b    = qkv_b + 3 * PSZ;

  cvt_all_k<<<XBLK + QTBLK + (DIM / 32) * (DIM / 32), 256, 0, stream>>>(
      x, Wqkv, Wproj, xb, wqkvt, wprojt);

  gemm_qkv<<<1152, 256, 0, stream>>>(xb, wqkvt, bqkv, qkv_b);

  attn_k<<<dim3(BATCH * HEADS, SEQ / 128), 512, 0, stream>>>(
      qkv_b, qkv_b + PSZ, qkv_b + 2 * PSZ, y_b);

  gemm_proj<<<384, 256, 0, stream>>>(y_b, wprojt, bproj, out);
}

// Round 11
// 173.386 us; speedup vs baseline: 1.0402x; 1.0402x over previous
//
#include <hip/hip_runtime.h>

typedef unsigned short u16;
typedef __attribute__((ext_vector_type(8))) short short8;
typedef __attribute__((ext_vector_type(4))) short short4v;
typedef __attribute__((ext_vector_type(2))) int int2v;
typedef __attribute__((ext_vector_type(4))) float f32x4;

#define DIM   768
#define HEADS 12
#define HD    64
#define BATCH 8
#define SEQ   1024
#define MTOK  (BATCH*SEQ)   /* 8192 */
#define NQKV  (3*DIM)       /* 2304 */
#define KP    72            /* attn P-region row stride (144B = 9*16B, b128-aligned) */
#define EPAD  66            /* gemm epilogue stage stride */
#define PSZ   ((size_t)BATCH*HEADS*SEQ*HD)   /* one of q/k/v */
#define SCQ   0.1803368801f /* hd^-0.5 * log2(e), folded into stored q */

__device__ __forceinline__ u16 f2bf(float f) {
  unsigned x = __float_as_uint(f);
  x += 0x7fffu + ((x >> 16) & 1u);      // RNE
  return (u16)(x >> 16);
}

__device__ __forceinline__ void gload16(const u16* g, u16* l) {
  __builtin_amdgcn_global_load_lds(
      (const __attribute__((address_space(1))) unsigned int*)g,
      (__attribute__((address_space(3))) unsigned int*)l, 16, 0, 0);
}

// ---------------- fused conversions: x->bf16, Wqkv^T, Wproj^T ----------------
#define XBLK 6144            /* MTOK*DIM/4/256 */
#define QTBLK 1728           /* (NQKV/32)*(DIM/32) */
__global__ void cvt_all_k(const float* __restrict__ x,
                          const float* __restrict__ Wqkv,
                          const float* __restrict__ Wproj,
                          u16* __restrict__ xb, u16* __restrict__ wqkvt,
                          u16* __restrict__ wprojt) {
  __shared__ u16 tile[32][33];
  const int blk = blockIdx.x;
  if (blk < XBLK) {
    const int i = blk * 256 + threadIdx.x;
    float4 f = ((const float4*)x)[i];
    short4v o;
    o.x = (short)f2bf(f.x); o.y = (short)f2bf(f.y);
    o.z = (short)f2bf(f.z); o.w = (short)f2bf(f.w);
    ((short4v*)xb)[i] = o;
    return;
  }
  const float* in; u16* out; int K, N, n0, k0;
  if (blk < XBLK + QTBLK) {
    const int t = blk - XBLK;
    in = Wqkv; out = wqkvt; K = DIM; N = NQKV;
    n0 = (t % (NQKV / 32)) * 32; k0 = (t / (NQKV / 32)) * 32;
  } else {
    const int t = blk - XBLK - QTBLK;
    in = Wproj; out = wprojt; K = DIM; N = DIM;
    n0 = (t % (DIM / 32)) * 32; k0 = (t / (DIM / 32)) * 32;
  }
  const int tx = threadIdx.x & 31, ty = threadIdx.x >> 5;
  #pragma unroll
  for (int i = 0; i < 32; i += 8)
    tile[ty + i][tx] = f2bf(in[(size_t)(k0 + ty + i) * N + n0 + tx]);
  __syncthreads();
  #pragma unroll
  for (int i = 0; i < 32; i += 8)
    out[(size_t)(n0 + ty + i) * K + k0 + tx] = tile[tx][ty + i];
}

// ---------------- GEMM1: qkv = x * Wqkv^T + b, 128x128 tile, BK=64 ----------------
// Round-10 proven: counted-vmcnt on the BK=64 frame (vmcnt(8) across barrier),
// 2 LDS buffers, 32 MFMA per barrier-pair. 680 TF = 2-barrier-class ceiling.
__global__ __launch_bounds__(256)
void gemm_qkv(const u16* __restrict__ A, const u16* __restrict__ Bt,
              const float* __restrict__ bias, u16* __restrict__ qkv) {
  __shared__ __align__(16) u16 smem[8 * 128 * 32];   // 64 KB: 2 half-buffers
  const int w = threadIdx.x >> 6, lane = threadIdx.x & 63;
  const int l15 = lane & 15, quad = lane >> 4;
  const int b_ = blockIdx.x;
  const int xcd = b_ & 7, j = b_ >> 3;
  const int m0 = ((j & 7) * 8 + xcd) * 128;   // 0..63 * 128
  const int n0 = (j >> 3) * 128;              // 0..17 * 128
  const int wm = (w >> 1) * 64, wn = (w & 1) * 64;

  f32x4 acc[4][4] = {};

  const int ar = threadIdx.x >> 2, ak = (threadIdx.x & 3) * 8;
  const u16* ga = A  + (size_t)(m0 + ar) * DIM + ak;
  const u16* gb = Bt + (size_t)(n0 + ar) * DIM + ak;
  const int lo = threadIdx.x * 8;

  auto qstage = [&](int c, int k0) {
    u16* base = smem + c * 16384;
    #pragma unroll
    for (int t = 0; t < 2; ++t) {
      gload16(ga + (size_t)t * 64 * DIM + k0,      base + lo + t * 2048);
      gload16(ga + (size_t)t * 64 * DIM + k0 + 32, base + 4096  + lo + t * 2048);
      gload16(gb + (size_t)t * 64 * DIM + k0,      base + 8192  + lo + t * 2048);
      gload16(gb + (size_t)t * 64 * DIM + k0 + 32, base + 12288 + lo + t * 2048);
    }
  };

  qstage(0, 0);   // batch 0 -> buf0

  #pragma unroll
  for (int it = 0; it < 12; ++it) {
    const int cur = it & 1;
    if (it < 11) qstage(cur ^ 1, (it + 1) * 64);   // batch it+1 -> buf^1
    if (it < 11) asm volatile("s_waitcnt vmcnt(8)" ::: "memory");
    else         asm volatile("s_waitcnt vmcnt(0)" ::: "memory");
    __builtin_amdgcn_s_barrier();

    const u16* hb = smem + cur * 16384;
    short8 af[4][2], bfr[4][2];
    #pragma unroll
    for (int kh = 0; kh < 2; ++kh) {
      const u16* lAh = hb + kh * 4096;
      const u16* lBh = hb + 8192 + kh * 4096;
      #pragma unroll
      for (int mt = 0; mt < 4; ++mt)
        af[mt][kh] = *(const short8*)&lAh[(wm + mt * 16 + l15) * 32 + quad * 8];
      #pragma unroll
      for (int nt = 0; nt < 4; ++nt)
        bfr[nt][kh] = *(const short8*)&lBh[(wn + nt * 16 + l15) * 32 + quad * 8];
    }

    asm volatile("s_waitcnt lgkmcnt(0)" ::: "memory");
    __builtin_amdgcn_s_barrier();

    #pragma unroll
    for (int kh = 0; kh < 2; ++kh)
      #pragma unroll
      for (int mt = 0; mt < 4; ++mt)
        #pragma unroll
        for (int nt = 0; nt < 4; ++nt)
          acc[mt][nt] = __builtin_amdgcn_mfma_f32_16x16x32_bf16(af[mt][kh], bfr[nt][kh], acc[mt][nt], 0, 0, 0);
  }

  const int bb = m0 >> 10;
  const int tb0 = (m0 & 1023) + wm;
  const int nh = n0 + wn;
  const int part = nh / DIM, idx = nh - part * DIM;
  const int h = idx >> 6;

  float bnl[4];
  #pragma unroll
  for (int nt = 0; nt < 4; ++nt) bnl[nt] = bias[nh + nt * 16 + l15];

  if (part < 2) {
    u16* dstbase = qkv + part * PSZ + ((size_t)(bb * HEADS + h) * SEQ + tb0) * HD;
    const float qsc = (part == 0) ? SCQ : 1.0f;
    const int erow = lane >> 3, ec8 = (lane & 7) * 8;
    #pragma unroll
    for (int mt = 0; mt < 4; ++mt) {
      u16* ep = smem + w * (16 * EPAD) + (mt & 1) * (4 * 16 * EPAD);
      #pragma unroll
      for (int nt = 0; nt < 4; ++nt)
        #pragma unroll
        for (int r = 0; r < 4; ++r)
          ep[(quad * 4 + r) * EPAD + nt * 16 + l15] = f2bf((acc[mt][nt][r] + bnl[nt]) * qsc);
      #pragma unroll
      for (int j2 = 0; j2 < 2; ++j2) {
        const int trow = j2 * 8 + erow;
        short8 vrow = *(const short8*)&ep[trow * EPAD + ec8];
        *(short8*)(dstbase + (size_t)(mt * 16 + trow) * HD + ec8) = vrow;
      }
    }
  } else {
    u16* vrow0 = qkv + 2 * PSZ + (size_t)(bb * HEADS + h) * HD * SEQ;
    #pragma unroll
    for (int nt = 0; nt < 4; ++nt) {
      const int d = nt * 16 + l15;
      u16* trow = vrow0 + (size_t)d * SEQ + tb0 + quad * 4;
      #pragma unroll
      for (int mt = 0; mt < 4; ++mt) {
        short4v pv;
        pv.x = (short)f2bf(acc[mt][nt][0] + bnl[nt]);
        pv.y = (short)f2bf(acc[mt][nt][1] + bnl[nt]);
        pv.z = (short)f2bf(acc[mt][nt][2] + bnl[nt]);
        pv.w = (short)f2bf(acc[mt][nt][3] + bnl[nt]);
        *(short4v*)(trow + mt * 16) = pv;
      }
    }
  }
}

// ---------------- GEMM2: out = y * Wproj^T + b (fp32 out, 128x128, BK=64) ----------------
// Round-8 proven: 64x64/wave, BK=64 2-phase dbuf, grid 384 (=8x48, XCD-swizzled),
// fully co-resident at 2 blocks/CU.
__global__ __launch_bounds__(256)
void gemm_proj(const u16* __restrict__ A, const u16* __restrict__ Bt,
               const float* __restrict__ bias, float* __restrict__ outF) {
  __shared__ __align__(16) u16 smem[8 * 128 * 32];   // 64 KB: 2 half-buffers
  const int w = threadIdx.x >> 6, lane = threadIdx.x & 63;
  const int l15 = lane & 15, quad = lane >> 4;
  const int b_ = blockIdx.x;
  const int xcd = b_ & 7, j = b_ >> 3;        // j 0..47
  const int m0 = ((j & 7) * 8 + xcd) * 128;   // 0..63 * 128
  const int n0 = (j >> 3) * 128;              // 0..5 * 128
  const int wm = (w >> 1) * 64, wn = (w & 1) * 64;

  f32x4 acc[4][4] = {};

  const int ar = threadIdx.x >> 2, ak = (threadIdx.x & 3) * 8;
  const u16* ga = A  + (size_t)(m0 + ar) * DIM + ak;
  const u16* gb = Bt + (size_t)(n0 + ar) * DIM + ak;
  const int lo = threadIdx.x * 8;

  auto pstage = [&](int c, int k0) {
    u16* base = smem + c * 16384;
    #pragma unroll
    for (int t = 0; t < 2; ++t) {
      gload16(ga + (size_t)t * 64 * DIM + k0,      base + lo + t * 2048);
      gload16(ga + (size_t)t * 64 * DIM + k0 + 32, base + 4096  + lo + t * 2048);
      gload16(gb + (size_t)t * 64 * DIM + k0,      base + 8192  + lo + t * 2048);
      gload16(gb + (size_t)t * 64 * DIM + k0 + 32, base + 12288 + lo + t * 2048);
    }
  };

  pstage(0, 0);
  __syncthreads();

  #pragma unroll
  for (int it = 0; it < 12; ++it) {
    const int cur = it & 1;
    if (it < 11) pstage(cur ^ 1, (it + 1) * 64);
    const u16* hb = smem + cur * 16384;
    #pragma unroll
    for (int kh = 0; kh < 2; ++kh) {
      const u16* lAh = hb + kh * 4096;
      const u16* lBh = hb + 8192 + kh * 4096;
      short8 af[4], bfr[4];
      #pragma unroll
      for (int mt = 0; mt < 4; ++mt)
        af[mt] = *(const short8*)&lAh[(wm + mt * 16 + l15) * 32 + quad * 8];
      #pragma unroll
      for (int nt = 0; nt < 4; ++nt)
        bfr[nt] = *(const short8*)&lBh[(wn + nt * 16 + l15) * 32 + quad * 8];
      #pragma unroll
      for (int mt = 0; mt < 4; ++mt)
        #pragma unroll
        for (int nt = 0; nt < 4; ++nt)
          acc[mt][nt] = __builtin_amdgcn_mfma_f32_16x16x32_bf16(af[mt], bfr[nt], acc[mt][nt], 0, 0, 0);
    }
    __syncthreads();
  }

  #pragma unroll
  for (int nt = 0; nt < 4; ++nt) {
    const int n = n0 + wn + nt * 16 + l15;
    const float bn = bias[n];
    #pragma unroll
    for (int mt = 0; mt < 4; ++mt)
      #pragma unroll
      for (int r = 0; r < 4; ++r) {
        const int m = m0 + wm + mt * 16 + quad * 4 + r;
        outF[(size_t)m * DIM + n] = acc[mt][nt][r] + bn;
      }
  }
}

// ---------------- flash attention: 8 waves = 4 row-groups x 2 key-halves ----------------
// gload_lds K/V staging (removes 2 ds_write_b128/thread/kc + 16 prefetch VGPRs):
// linear [64][64] double-buffered tiles with XOR chunk-swizzle (chunk ^= row&7)
// applied to BOTH the per-lane global source (m173: gload_lds dest is linear)
// and the fragment-read addresses. Bank cost equals the old KP=72 layout
// (8 lanes/16B-span = b128 structural floor); the win is the removed writes.
// Counted vmcnt (round-10 pattern): stage(kc+1) issued before compute(kc),
// vmcnt(2) waits only batch kc -- batch kc+1 stays in flight across the barrier.
__global__ __launch_bounds__(512, 4)
void attn_k(const u16* __restrict__ qb, const u16* __restrict__ kb,
            const u16* __restrict__ vtb, u16* __restrict__ yb) {
  const int bh = blockIdx.x, qt = blockIdx.y;
  const int tid = threadIdx.x;
  const int w = tid >> 6, lane = tid & 63;
  const int l15 = lane & 15, quad = lane >> 4;
  const int rg = w & 3;          // row-group: 32 rows each
  const int kh = w >> 2;         // key-half: keys kh*32..kh*32+31
  const int nt0 = kh * 2;

  __shared__ __align__(16) u16 smem[26624];   // 53248 B
  // main loop (u16 offsets): K0 @0, V0 @4096, K1 @8192, V1 @12288 (each [64][64])
  //                          lPq @16384 + rg*2304  ([32][KP] per rg)
  // epilogue (aliases dead regions): fo = f32[128][68] @0 (17408 u16, over bufs+lPq head)
  //                                  stg @17408 + rg*2304 (over lPq tail)
  u16* lPq = smem + 16384 + rg * 2304;
  u16* stg = smem + 17408 + rg * 2304;
  float* fo = (float*)smem;

  // Q fragments: rows qt*128 + rg*32 + qg*16 + l15
  const u16* qrow = qb + ((size_t)bh * SEQ + qt * 128 + rg * 32 + l15) * HD;
  short8 aq[2][2];
  #pragma unroll
  for (int qg = 0; qg < 2; ++qg) {
    aq[qg][0] = *(const short8*)(qrow + (size_t)qg * 16 * HD + quad * 8);
    aq[qg][1] = *(const short8*)(qrow + (size_t)qg * 16 * HD + 32 + quad * 8);
  }

  f32x4 o[2][4] = {};     // [qg][d-group] partial PV over this wave's 32 keys
  f32x4 sum[2] = {};      // [qg] partial row-sums (MFMA vs ones)

  const u16* kcbase = kb + (size_t)bh * SEQ * HD;
  const u16* vbase  = vtb + (size_t)bh * HD * SEQ;

  // staging: thread tid owns LDS slot tid*16B of each tile; its global source
  // is the 16B chunk that BELONGS there under the XOR swizzle.
  const int srow = tid >> 3;
  const int schunk = (tid & 7) ^ (srow & 7);
  const u16* kgs = kcbase + (size_t)srow * HD + schunk * 8;   // + kc*4096
  const u16* vgs = vbase + (size_t)srow * SEQ + schunk * 8;   // + kc*64
  const int dst = tid * 8;   // u16 offset within a tile

  auto stage = [&](int c, int kc) {
    gload16(kgs + kc * 4096, smem + c * 8192 + dst);
    gload16(vgs + kc * 64,   smem + c * 8192 + 4096 + dst);
  };

  short8 ones;
  #pragma unroll
  for (int i = 0; i < 8; ++i) ones[i] = (short)0x3f80;   // bf16 1.0

  stage(0, 0);

  for (int kc = 0; kc < 16; ++kc) {
    const int cur = kc & 1;
    if (kc < 15) stage(cur ^ 1, kc + 1);
    // wait ONLY batch kc (2 loads); batch kc+1 stays in flight across the barrier
    if (kc < 15) asm volatile("s_waitcnt vmcnt(2)" ::: "memory");
    else         asm volatile("s_waitcnt vmcnt(0)" ::: "memory");
    __builtin_amdgcn_s_barrier();

    const u16* lK = smem + cur * 8192;
    const u16* lV = lK + 4096;
    const int sx = l15 & 7;   // row&7 for both K (key) and V (d) fragment rows

    // K fragments for this wave's 32 keys (shared across qg), swizzled chunks
    short8 akf[2][2];
    #pragma unroll
    for (int i = 0; i < 2; ++i) {
      const int key = (nt0 + i) * 16 + l15;
      akf[i][0] = *(const short8*)&lK[key * 64 + ((quad ^ sx) * 8)];
      akf[i][1] = *(const short8*)&lK[key * 64 + (((4 + quad) ^ sx) * 8)];
    }

    // QK^T + softmax numerators for both qg
    #pragma unroll
    for (int qg = 0; qg < 2; ++qg) {
      f32x4 s0 = {}, s1 = {};
      __builtin_amdgcn_s_setprio(1);
      s0 = __builtin_amdgcn_mfma_f32_16x16x32_bf16(akf[0][0], aq[qg][0], s0, 0, 0, 0);
      s0 = __builtin_amdgcn_mfma_f32_16x16x32_bf16(akf[0][1], aq[qg][1], s0, 0, 0, 0);
      s1 = __builtin_amdgcn_mfma_f32_16x16x32_bf16(akf[1][0], aq[qg][0], s1, 0, 0, 0);
      s1 = __builtin_amdgcn_mfma_f32_16x16x32_bf16(akf[1][1], aq[qg][1], s1, 0, 0, 0);
      __builtin_amdgcn_s_setprio(0);
      #pragma unroll
      for (int i = 0; i < 2; ++i) {
        const f32x4 s = i ? s1 : s0;
        float p0 = __builtin_amdgcn_exp2f(s[0]);
        float p1 = __builtin_amdgcn_exp2f(s[1]);
        float p2 = __builtin_amdgcn_exp2f(s[2]);
        float p3 = __builtin_amdgcn_exp2f(s[3]);
        int2v pkk;
        pkk.x = (int)__builtin_amdgcn_perm(__float_as_uint(p1), __float_as_uint(p0), 0x07060302u);
        pkk.y = (int)__builtin_amdgcn_perm(__float_as_uint(p3), __float_as_uint(p2), 0x07060302u);
        *(int2v*)&lPq[(qg * 16 + l15) * KP + (nt0 + i) * 16 + quad * 4] = pkk;
      }
    }

    // V fragments (this key-half), shared across qg, swizzled chunks
    short8 bv[4];
    #pragma unroll
    for (int ntd = 0; ntd < 4; ++ntd)
      bv[ntd] = *(const short8*)&lV[(ntd * 16 + l15) * 64 + (((kh * 4 + quad) ^ sx) * 8)];

    #pragma unroll
    for (int qg = 0; qg < 2; ++qg) {
      const short8 ap = *(const short8*)&lPq[(qg * 16 + l15) * KP + kh * 32 + quad * 8];
      __builtin_amdgcn_s_setprio(1);
      #pragma unroll
      for (int ntd = 0; ntd < 4; ++ntd)
        o[qg][ntd] = __builtin_amdgcn_mfma_f32_16x16x32_bf16(ap, bv[ntd], o[qg][ntd], 0, 0, 0);
      sum[qg] = __builtin_amdgcn_mfma_f32_16x16x32_bf16(ap, ones, sum[qg], 0, 0, 0);
      __builtin_amdgcn_s_setprio(0);
    }

    // WAR fence: all lanes' LDS reads of buf[cur] done before anyone can issue
    // the DMA that overwrites it (at iter kc+1's stage)
    asm volatile("s_waitcnt lgkmcnt(0)" ::: "memory");
    __builtin_amdgcn_s_barrier();
  }

  // ---- combine key-halves: kh=1 publishes partials, kh=0 finishes ----
  if (kh == 1) {
    #pragma unroll
    for (int qg = 0; qg < 2; ++qg)
      #pragma unroll
      for (int r = 0; r < 4; ++r) {
        const int row = rg * 32 + qg * 16 + quad * 4 + r;
        #pragma unroll
        for (int ntd = 0; ntd < 4; ++ntd)
          fo[row * 68 + ntd * 16 + l15] = o[qg][ntd][r];
        if (l15 == 0) fo[row * 68 + 64] = sum[qg][r];
      }
  }
  __syncthreads();

  if (kh == 0) {
    const int b = bh / HEADS, h = bh % HEADS;
    #pragma unroll
    for (int qg = 0; qg < 2; ++qg)
      #pragma unroll
      for (int r = 0; r < 4; ++r) {
        const int lrow = qg * 16 + quad * 4 + r;
        const int row = rg * 32 + lrow;
        const float s = sum[qg][r] + fo[row * 68 + 64];
        const float inv = 1.0f / s;
        #pragma unroll
        for (int ntd = 0; ntd < 4; ++ntd) {
          const float v = (o[qg][ntd][r] + fo[row * 68 + ntd * 16 + l15]) * inv;
          stg[lrow * KP + ntd * 16 + l15] = f2bf(v);
        }
      }
    u16* dst2 = yb + ((size_t)b * SEQ + qt * 128 + rg * 32) * DIM + h * HD;
    const int erow = lane >> 3, ec8 = (lane & 7) * 8;
    #pragma unroll
    for (int j = 0; j < 4; ++j) {
      const int trow = j * 8 + erow;
      short8 vrow = *(const short8*)&stg[trow * KP + ec8];
      *(short8*)(dst2 + (size_t)trow * DIM + ec8) = vrow;
    }
  }
}

// ---------------- launcher ----------------
extern "C" void kernel_launch(void* const* d_in, const int* in_sizes, int n_in,
                              void* d_out, int out_size, void* d_ws, size_t ws_size,
                              hipStream_t stream) {
  const float* x     = (const float*)d_in[0];
  const float* Wqkv  = (const float*)d_in[1];
  const float* bqkv  = (const float*)d_in[2];
  const float* Wproj = (const float*)d_in[3];
  const float* bproj = (const float*)d_in[4];
  float* out = (float*)d_out;

  u16* xb     = (u16*)d_ws;                       // 8192*768
  u16* wqkvt  = xb + (size_t)MTOK * DIM;
  u16* wprojt = wqkvt + (size_t)NQKV * DIM;
  u16* qkv_b  = wprojt + (size_t)DIM * DIM;       // q,k: [t][d]; v-slot holds vt [d][t]
  u16* y_b    = qkv_b + 3 * PSZ;

  cvt_all_k<<<XBLK + QTBLK + (DIM / 32) * (DIM / 32), 256, 0, stream>>>(
      x, Wqkv, Wproj, xb, wqkvt, wprojt);

  gemm_qkv<<<1152, 256, 0, stream>>>(xb, wqkvt, bqkv, qkv_b);

  attn_k<<<dim3(BATCH * HEADS, SEQ / 128), 512, 0, stream>>>(
      qkv_b, qkv_b + PSZ, qkv_b + 2 * PSZ, y_b);

  gemm_proj<<<384, 256, 0, stream>>>(y_b, wprojt, bproj, out);
}